// Round 11
// baseline (534.949 us; speedup 1.0000x reference)
//
#include <hip/hip_runtime.h>
#include <math.h>

constexpr int Bv = 4, Sv = 2048, Ev = 1024, Hv = 16, Dv = 64;
constexpr int BS = Bv * Sv;     // 8192
constexpr int E3 = 3 * Ev;      // 3072
constexpr int E2 = 2 * Ev;      // 2048 (gemm1 output: q,k only; v collapsed)

typedef unsigned short ushort_t;
typedef _Float16 half8 __attribute__((ext_vector_type(8)));
typedef float floatx4 __attribute__((ext_vector_type(4)));

__device__ __forceinline__ floatx4 mfma16(half8 a, half8 b, floatx4 c) {
    return __builtin_amdgcn_mfma_f32_16x16x32_f16(a, b, c, 0, 0, 0);
}
__device__ __forceinline__ ushort_t f2h(float x) {
    _Float16 h = (_Float16)x;
    return *(ushort_t*)&h;
}
__device__ __forceinline__ unsigned pkrtz(float a, float b) {
    auto p = __builtin_amdgcn_cvt_pkrtz(a, b);
    return *(unsigned*)&p;
}
typedef const __attribute__((address_space(1))) unsigned int* gas_t;
typedef __attribute__((address_space(3))) unsigned int* las_t;
__device__ __forceinline__ void gl_lds16(const void* g, void* l) {
    __builtin_amdgcn_global_load_lds((gas_t)g, (las_t)l, 16, 0, 0);
}
// swizzled offset (ushort units) in a [rows][64]-half LDS tile; 16B-chunk xor
__device__ __forceinline__ int sw64(int row, int col) {
    return row * 64 + (((col >> 3) ^ (row & 7)) << 3) + (col & 7);
}
#define SOFTMAX_SC (0.125f * 1.44269504f)   // 1/sqrt(D) * log2(e), folded into q2

// ---------------------------------------------------------------------------
// Fused prep: all independent setup work in ONE dispatch, block-range switched.
// ---------------------------------------------------------------------------
constexpr int PS0 = 8192, PS1 = 11264, PS2 = 12288, PS3 = 12544,
              PS4 = 12800, PS5 = 13056;

__device__ __forceinline__ void conv_seg(const float* __restrict__ s,
                                         ushort_t* __restrict__ d, int i) {
    float4 v = ((const float4*)s)[i];
    ((ushort4*)d)[i] = make_ushort4(f2h(v.x), f2h(v.y), f2h(v.z), f2h(v.w));
}

__global__ __launch_bounds__(256)
void prep_k(const float* __restrict__ x, const float* __restrict__ w1,
            const float* __restrict__ b1,
            ushort_t* __restrict__ xh, ushort_t* __restrict__ w1h,
            ushort_t* __restrict__ woh, const float* __restrict__ wo,
            float* __restrict__ rope, ushort_t* __restrict__ wvt,
            float* __restrict__ bv2)
{
    __shared__ ushort_t t[64][65];
    const int blk = blockIdx.x, tid = threadIdx.x;
    if (blk < PS0) { conv_seg(x, xh, blk * 256 + tid); return; }
    if (blk < PS1) { conv_seg(w1, w1h, (blk - PS0) * 256 + tid); return; }
    if (blk < PS2) { conv_seg(wo, woh, (blk - PS1) * 256 + tid); return; }
    if (blk < PS3) {
        const int i = (blk - PS2) * 256 + tid;          // over S*32
        const int s = i >> 5, f = i & 31;
        const float fr = exp2f((float)f * -0.4152410118609203f);
        float sn, cs;
        sincosf((float)s * fr, &sn, &cs);
        ((float2*)rope)[i] = make_float2(cs, sn);
        return;
    }
    if (blk < PS4) {
        // Wv^T: w1 rows [2048,3072) fp32 -> wvt[k][n] fp16
        const int lin = blk - PS3;
        const int i0 = (lin >> 4) * 64, j0 = (lin & 15) * 64;
        #pragma unroll
        for (int p = 0; p < 16; ++p) {
            const int idx = p * 256 + tid;
            const int i = idx >> 6, j = idx & 63;       // read coalesced over j
            t[j][i] = f2h(w1[(size_t)(2048 + i0 + i) * 1024 + j0 + j]);
        }
        __syncthreads();
        #pragma unroll
        for (int p = 0; p < 16; ++p) {
            const int idx = p * 256 + tid;
            const int j = idx >> 6, i = idx & 63;       // write coalesced over i
            wvt[(size_t)(j0 + j) * 1024 + i0 + i] = t[j][i];
        }
        return;
    }
    {   // bv2[row] = bv[row] + sum_j Wv[row][j]*bv[j]
        const int row = (blk - PS4) * 4 + (tid >> 6);
        const int lane = tid & 63;
        const float* wr = w1 + (size_t)(2048 + row) * 1024;
        const float* bvp = b1 + 2048;
        float p = 0.f;
        for (int j = lane; j < 1024; j += 64) p += wr[j] * bvp[j];
        #pragma unroll
        for (int o = 32; o; o >>= 1) p += __shfl_down(p, o);
        if (lane == 0) bv2[row] = p + bvp[row];
    }
}

// ---------------------------------------------------------------------------
// wv2 = Wv @ Wv (fp16 in, fp32 accum, pkrtz out), 64x64 tiles, 256 blocks.
// ---------------------------------------------------------------------------
__global__ __launch_bounds__(256)
void wv2_k(const ushort_t* __restrict__ wv, const ushort_t* __restrict__ wvt,
           ushort_t* __restrict__ wv2)
{
    const int tid = threadIdx.x;
    const int lane = tid & 63, wid = tid >> 6;
    const int ln = lane & 15, quad = lane >> 4;
    const int r0 = blockIdx.y * 64 + wid * 16;   // output rows (this wave)
    const int c0 = blockIdx.x * 64;              // output cols

    const ushort_t* Ar = wv + (size_t)(r0 + ln) * 1024 + quad * 8;
    const ushort_t* Br = wvt + (size_t)(c0 + ln) * 1024 + quad * 8;

    const floatx4 Z = {0.f, 0.f, 0.f, 0.f};
    floatx4 acc[4] = {Z, Z, Z, Z};
    for (int k0 = 0; k0 < 1024; k0 += 32) {
        const half8 af = *(const half8*)(Ar + k0);
        #pragma unroll
        for (int nt = 0; nt < 4; ++nt) {
            const half8 bf = *(const half8*)(Br + (size_t)nt * 16 * 1024 + k0);
            acc[nt] = mfma16(bf, af, acc[nt]);
        }
    }
    #pragma unroll
    for (int nt = 0; nt < 4; ++nt) {
        uint2 o;
        o.x = pkrtz(acc[nt][0], acc[nt][1]);
        o.y = pkrtz(acc[nt][2], acc[nt][3]);
        *(uint2*)(wv2 + (size_t)(r0 + ln) * 1024 + c0 + nt * 16 + quad * 4) = o;
    }
}

// ---------------------------------------------------------------------------
// fp16 GEMM, C^T register layout (lane owns 4 consecutive n), fp32 accum.
// EPI 0: +bias, RoPE on q,k parts (table) -> qkv (B,S,E2) fp16, row stride N
// EPI 1: +bias (+SC on q) -> qkv2 [part][b][h][s][d] for q,k; v-part computed
//        from A2=xh with W2=Wv2 / bias2=bv2 -> outv [b][h][d][s]
// EPI 2: +bias -> fp32 outf (row stride N)
// ---------------------------------------------------------------------------
template<int EPI>
__global__ __launch_bounds__(256)
void gemm_f16(const ushort_t* __restrict__ A, const ushort_t* __restrict__ A2,
              const ushort_t* __restrict__ W, const ushort_t* __restrict__ W2,
              const float* __restrict__ bias, const float* __restrict__ bias2,
              const float* __restrict__ rope,
              ushort_t* __restrict__ outh, ushort_t* __restrict__ outv,
              float* __restrict__ outf, int N, int K, int lda)
{
    __shared__ __align__(16) ushort_t As[128 * 32], Bs[128 * 32];
    __shared__ __align__(16) ushort_t Es[64 * 136];

    const int tid = threadIdx.x;
    const int lane = tid & 63, wid = tid >> 6;
    const int ln = lane & 15, quad = lane >> 4;
    const int n0 = blockIdx.x * 128, m0 = blockIdx.y * 128;
    const int wm = wid & 1, wn = wid >> 1;
    const int part = n0 >> 10;                         // 0=q 1=k 2=v

    // per-part operand selection (block-uniform)
    const ushort_t* Ap = A;  int ldaa = lda; int acol = 0;
    const ushort_t* Wp = W;
    const float* bp = bias;
    int nW = n0;                                       // row offset into Wp/bp
    if (EPI == 1) {
        if (part == 2) { Ap = A2; ldaa = Ev; Wp = W2; bp = bias2; nW = n0 - 2048; }
        else acol = part << 10;
    }

    const int f0 = wid * 1024 + lane * 8, f1 = f0 + 512;
    const int r0 = f0 >> 5, c0 = f0 & 31, r1 = f1 >> 5, c1 = f1 & 31;
    const size_t a0 = (size_t)(m0 + r0) * ldaa + acol + c0;
    const size_t a1 = (size_t)(m0 + r1) * ldaa + acol + c1;
    const size_t w0 = (size_t)(nW + r0) * K + c0;
    const size_t w1 = (size_t)(nW + r1) * K + c1;
    const int l0 = wid * 1024, l1 = wid * 1024 + 512;

    const floatx4 Z = {0.f, 0.f, 0.f, 0.f};
    floatx4 acc[4][4];
    #pragma unroll
    for (int i = 0; i < 4; ++i)
        #pragma unroll
        for (int j = 0; j < 4; ++j) acc[i][j] = Z;

    const int abase = (wm * 64 + ln) * 32 + quad * 8;
    const int bbase = (wn * 64 + ln) * 32 + quad * 8;

    for (int k0 = 0; k0 < K; k0 += 32) {
        gl_lds16(Ap + a0 + k0, As + l0);
        gl_lds16(Ap + a1 + k0, As + l1);
        gl_lds16(Wp + w0 + k0, Bs + l0);
        gl_lds16(Wp + w1 + k0, Bs + l1);
        __syncthreads();
        half8 af[4], bf[4];
        #pragma unroll
        for (int t = 0; t < 4; ++t) {
            af[t] = *(const half8*)(As + abase + t * 512);
            bf[t] = *(const half8*)(Bs + bbase + t * 512);
        }
        // C^T: acc[mt][nt] holds C[m = m0+wm*64+mt*16+ln][n = n0+wn*64+nt*16+quad*4+reg]
        #pragma unroll
        for (int mt = 0; mt < 4; ++mt)
            #pragma unroll
            for (int nt = 0; nt < 4; ++nt)
                acc[mt][nt] = mfma16(bf[nt], af[mt], acc[mt][nt]);
        __syncthreads();
    }

    // bias: n depends on reg -> float4 per nt
    #pragma unroll
    for (int nt = 0; nt < 4; ++nt) {
        const float4 bb = *(const float4*)(bp + nW + wn * 64 + nt * 16 + quad * 4);
        #pragma unroll
        for (int mt = 0; mt < 4; ++mt) {
            acc[mt][nt][0] += bb.x; acc[mt][nt][1] += bb.y;
            acc[mt][nt][2] += bb.z; acc[mt][nt][3] += bb.w;
        }
    }

    if (EPI == 2) {
        #pragma unroll
        for (int mt = 0; mt < 4; ++mt)
            #pragma unroll
            for (int nt = 0; nt < 4; ++nt)
                *(floatx4*)(outf + (size_t)(m0 + wm * 64 + mt * 16 + ln) * N
                            + n0 + wn * 64 + nt * 16 + quad * 4) = acc[mt][nt];
        return;
    }

    // pack fp16 pairs (with RoPE / SC applied in-register)
    uint2 pk[4][4];
    if (EPI == 0 && part < 2) {
        // d = nt*16 + quad*4 + reg (mod 64); freq index = d&31; partner = nt^2
        #pragma unroll
        for (int mt = 0; mt < 4; ++mt) {
            const int s = (m0 + wm * 64 + mt * 16 + ln) & (Sv - 1);
            float sn[2][4], cs[2][4];
            #pragma unroll
            for (int p2 = 0; p2 < 2; ++p2) {
                const float* tb = rope + (size_t)(s * 32 + p2 * 16 + quad * 4) * 2;
                const float4 t0 = *(const float4*)(tb);
                const float4 t1 = *(const float4*)(tb + 4);
                cs[p2][0] = t0.x; sn[p2][0] = t0.y;
                cs[p2][1] = t0.z; sn[p2][1] = t0.w;
                cs[p2][2] = t1.x; sn[p2][2] = t1.y;
                cs[p2][3] = t1.z; sn[p2][3] = t1.w;
            }
            #pragma unroll
            for (int nt = 0; nt < 4; ++nt) {
                float v[4];
                #pragma unroll
                for (int reg = 0; reg < 4; ++reg) {
                    const float self = acc[mt][nt][reg];
                    const float partner = acc[mt][nt ^ 2][reg];
                    const float rot = (nt < 2) ? -partner : partner;
                    v[reg] = self * cs[nt & 1][reg] + rot * sn[nt & 1][reg];
                }
                pk[mt][nt].x = pkrtz(v[0], v[1]);
                pk[mt][nt].y = pkrtz(v[2], v[3]);
            }
        }
    } else {
        const float sc = (EPI == 1 && part == 0) ? SOFTMAX_SC : 1.0f;
        #pragma unroll
        for (int mt = 0; mt < 4; ++mt)
            #pragma unroll
            for (int nt = 0; nt < 4; ++nt) {
                pk[mt][nt].x = pkrtz(acc[mt][nt][0] * sc, acc[mt][nt][1] * sc);
                pk[mt][nt].y = pkrtz(acc[mt][nt][2] * sc, acc[mt][nt][3] * sc);
            }
    }

    // two passes (wm halves) through Es[64][136], then coalesced global stores
    for (int pass = 0; pass < 2; ++pass) {
        if (wm == pass) {
            #pragma unroll
            for (int mt = 0; mt < 4; ++mt)
                #pragma unroll
                for (int nt = 0; nt < 4; ++nt)
                    *(uint2*)(Es + (mt * 16 + ln) * 136 + wn * 64 + nt * 16 + quad * 4)
                        = pk[mt][nt];
        }
        __syncthreads();
        if (EPI == 0 || part < 2) {
            // each thread owns 32 halves = 4 x uint4 (uint4 = 8 ushorts)
            const int row = tid >> 2, coff = (tid & 3) * 32;
            uint4 u0 = *(const uint4*)(Es + row * 136 + coff);
            uint4 u1 = *(const uint4*)(Es + row * 136 + coff + 8);
            uint4 u2 = *(const uint4*)(Es + row * 136 + coff + 16);
            uint4 u3 = *(const uint4*)(Es + row * 136 + coff + 24);
            if (EPI == 0) {
                ushort_t* dst = outh + (size_t)(m0 + pass * 64 + row) * N + n0 + coff;
                *(uint4*)dst = u0; *(uint4*)(dst + 8) = u1;
                *(uint4*)(dst + 16) = u2; *(uint4*)(dst + 24) = u3;
            } else {
                const int b = m0 >> 11;
                const int s = (m0 & (Sv - 1)) + pass * 64 + row;
                const int h = ((n0 & (Ev - 1)) >> 6) + (coff >> 6);
                const int d0 = coff & 63;
                ushort_t* dst = outh + ((((size_t)part * Bv + b) * Hv + h) * Sv + s) * Dv + d0;
                *(uint4*)dst = u0; *(uint4*)(dst + 8) = u1;
                *(uint4*)(dst + 16) = u2; *(uint4*)(dst + 24) = u3;
            }
        } else {
            // v-part: transposed readback -> outv [b][h][d][s]
            const int dl = tid >> 1, sc0 = (tid & 1) * 32;
            ushort_t tmp[32];
            #pragma unroll
            for (int i = 0; i < 32; ++i) tmp[i] = Es[(sc0 + i) * 136 + dl];
            const int b = m0 >> 11;
            const int h = ((n0 & (Ev - 1)) >> 6) + (dl >> 6);
            const int d = dl & 63;
            ushort_t* dst = outv + (((size_t)b * Hv + h) * Dv + d) * Sv
                            + (m0 & (Sv - 1)) + pass * 64 + sc0;
            *(uint4*)dst = *(uint4*)&tmp[0];
            *(uint4*)(dst + 8) = *(uint4*)&tmp[8];
            *(uint4*)(dst + 16) = *(uint4*)&tmp[16];
            *(uint4*)(dst + 24) = *(uint4*)&tmp[24];
        }
        __syncthreads();
    }
}

// ---------------------------------------------------------------------------
// Flash attention, 16x16 S^T formulation, BARRIER-FREE.
// R9's head-locality XCD remap made each XCD's K/V working set (8 head-batches
// x 512KB = 4MB) L2-resident (FETCH 139MB -> 24.6MB measured). With K/V in L2,
// LDS staging + its two barriers + lgkmcnt drain are pure overhead (m169
// pattern): kf/va fragments now load STRAIGHT FROM GLOBAL (L2-hit ~200cyc,
// hidden across 16 independent waves/CU). Ps stays in LDS but is wave-private
// (rows wid*32..+31) -> NO barriers anywhere in the K-loop; every wave is
// self-paced, stalls overlap across waves instead of gating 4-wave lockstep.
// ---------------------------------------------------------------------------
__global__ __launch_bounds__(256)
void attn_f16(const ushort_t* __restrict__ qkv2, const ushort_t* __restrict__ v2t,
              ushort_t* __restrict__ ctx)
{
    __shared__ __align__(16) ushort_t Ps[128 * 64];   // [q][key], swizzled, wave-private rows

    const int tid = threadIdx.x;
    const int lane = tid & 63, wid = tid >> 6;
    const int ln = lane & 15, quad = lane >> 4;
    // ---- head-locality XCD remap (bijective on [0,1024)) ----
    const int L = blockIdx.x + 16 * (blockIdx.y + 16 * blockIdx.z);
    const int hb = (L & 7) * 8 + (L >> 7);    // head-batch [0,64), 8 per XCD
    const int q0 = ((L >> 3) & 15) * 128;
    const int h = hb & 15, b = hb >> 4;
    const size_t plane = (size_t)Bv * Hv * Sv * Dv;
    const size_t hoff = ((size_t)b * Hv + h) * ((size_t)Sv * Dv);
    const ushort_t* Q = qkv2 + hoff;
    const ushort_t* Kp = qkv2 + plane + hoff;
    const ushort_t* Vt = v2t + ((size_t)b * Hv + h) * ((size_t)Dv * Sv);

    // Q fragments (B-operand) straight from global: B[n=ln -> q][k=quad*8+j -> d]
    half8 qa[2][2];
    #pragma unroll
    for (int qt = 0; qt < 2; ++qt)
        #pragma unroll
        for (int kh = 0; kh < 2; ++kh)
            qa[qt][kh] = *(const half8*)(Q + (size_t)(q0 + wid * 32 + qt * 16 + ln) * Dv
                                         + kh * 32 + quad * 8);

    // ones-row A fragment for l accumulation: A[m=ln][k] = (ln==0)
    half8 aones;
    #pragma unroll
    for (int j = 0; j < 8; ++j) aones[j] = (_Float16)(ln == 0 ? 1.0f : 0.0f);

    const floatx4 Z = {0.f, 0.f, 0.f, 0.f};
    floatx4 O[2][4], lacc[2];
    #pragma unroll
    for (int qt = 0; qt < 2; ++qt) {
        lacc[qt] = Z;
        #pragma unroll
        for (int dt = 0; dt < 4; ++dt) O[qt][dt] = Z;
    }

    for (int kb = 0; kb < Sv; kb += 64) {
        // ---- K fragments straight from global (L2-resident) ----
        half8 kf[4][2];
        #pragma unroll
        for (int kt = 0; kt < 4; ++kt) {
            const ushort_t* krow = Kp + (size_t)(kb + kt * 16 + ln) * Dv + quad * 8;
            kf[kt][0] = *(const half8*)(krow);
            kf[kt][1] = *(const half8*)(krow + 32);
        }

        // ---- S^T = K Q^T : st[kt][qt]; lane: key = kt*16+quad*4+reg, q-col = ln
        floatx4 st[4][2];
        #pragma unroll
        for (int kt = 0; kt < 4; ++kt)
            #pragma unroll
            for (int qt = 0; qt < 2; ++qt) {
                st[kt][qt] = mfma16(kf[kt][0], qa[qt][0], Z);
                st[kt][qt] = mfma16(kf[kt][1], qa[qt][1], st[kt][qt]);
            }

        // ---- p = exp2(s), pack, store P[q][key] (wave-private rows) ----
        #pragma unroll
        for (int qt = 0; qt < 2; ++qt) {
            const int q = wid * 32 + qt * 16 + ln;
            #pragma unroll
            for (int kt = 0; kt < 4; ++kt) {
                uint2 pkv;
                pkv.x = pkrtz(exp2f(st[kt][qt][0]), exp2f(st[kt][qt][1]));
                pkv.y = pkrtz(exp2f(st[kt][qt][2]), exp2f(st[kt][qt][3]));
                *(uint2*)(Ps + sw64(q, kt * 16 + quad * 4)) = pkv;
            }
        }

        // ---- V fragments straight from global (L2-resident) ----
        half8 va[4][2];
        #pragma unroll
        for (int dt = 0; dt < 4; ++dt) {
            const ushort_t* vrow = Vt + (size_t)(dt * 16 + ln) * Sv + kb + quad * 8;
            va[dt][0] = *(const half8*)(vrow);
            va[dt][1] = *(const half8*)(vrow + 32);
        }

        // ---- O^T += V^T P^T ; l += ones-row . P ----
        #pragma unroll
        for (int qt = 0; qt < 2; ++qt) {
            const int q = wid * 32 + qt * 16 + ln;
            half8 pb0 = *(const half8*)(Ps + sw64(q, quad * 8));
            half8 pb1 = *(const half8*)(Ps + sw64(q, 32 + quad * 8));
            #pragma unroll
            for (int dt = 0; dt < 4; ++dt) {
                O[qt][dt] = mfma16(va[dt][0], pb0, O[qt][dt]);
                O[qt][dt] = mfma16(va[dt][1], pb1, O[qt][dt]);
            }
            lacc[qt] = mfma16(aones, pb0, lacc[qt]);
            lacc[qt] = mfma16(aones, pb1, lacc[qt]);
        }
    }

    // epilogue: l lives in D[0][q] = lanes 0..15 (quad 0, reg 0); broadcast
    #pragma unroll
    for (int qt = 0; qt < 2; ++qt) {
        const float lq = __shfl(lacc[qt][0], ln);
        const float il = 1.0f / lq;
        const int q = q0 + wid * 32 + qt * 16 + ln;
        #pragma unroll
        for (int dt = 0; dt < 4; ++dt) {
            uint2 ov;
            ov.x = pkrtz(O[qt][dt][0] * il, O[qt][dt][1] * il);
            ov.y = pkrtz(O[qt][dt][2] * il, O[qt][dt][3] * il);
            *(uint2*)(ctx + ((size_t)(b * Sv + q)) * Ev + h * Dv + dt * 16 + quad * 4) = ov;
        }
    }
}

// ---------------------------------------------------------------------------
extern "C" void kernel_launch(void* const* d_in, const int* in_sizes, int n_in,
                              void* d_out, int out_size, void* d_ws, size_t ws_size,
                              hipStream_t stream) {
    const float* x  = (const float*)d_in[0];
    const float* w1 = (const float*)d_in[1];
    const float* b1 = (const float*)d_in[2];
    const float* wo = (const float*)d_in[3];
    const float* bo = (const float*)d_in[4];
    float* out = (float*)d_out;

    char* w = (char*)d_ws;
    ushort_t* xh   = (ushort_t*)(w + 0);            // 16,777,216
    ushort_t* w1h  = (ushort_t*)(w + 16777216);     //  6,291,456
    ushort_t* woh  = (ushort_t*)(w + 23068672);     //  2,097,152
    ushort_t* qkv  = (ushort_t*)(w + 25165824);     // 33,554,432 (B,S,E2): q,k only
    ushort_t* qkv2 = (ushort_t*)(w + 75497472);     // [2][b][h][s][d] used (32MB)
    ushort_t* v2t  = (ushort_t*)(w + 125829120);    // 16,777,216 [b][h][d][s]
    ushort_t* ctx  = (ushort_t*)(w + 142606336);    // 16,777,216 (B,S,E)
    float* rope = (float*)(w + 75497472);           // 512 KB, dead before gemm2
    ushort_t* wvt = (ushort_t*)(w + 75497472 + 33554432);             // 2MB
    ushort_t* wv2 = (ushort_t*)(w + 75497472 + 33554432 + 2097152);   // 2MB
    float*    bv2 = (float*)   (w + 75497472 + 33554432 + 4194304);   // 4KB

    dim3 blk(256);
    // fused prep: convs + rope table + Wv^T + bv2, one dispatch
    prep_k<<<dim3(PS5), blk, 0, stream>>>(x, w1, b1, xh, w1h, woh, wo,
                                          rope, wvt, bv2);
    // Wv2 = Wv @ Wv
    wv2_k<<<dim3(16, 16), blk, 0, stream>>>(w1h + (size_t)2048 * 1024, wvt, wv2);

    // GEMM1 + bias + RoPE (table) -> qkv (B,S,E2) fp16  (q,k only; v collapsed)
    gemm_f16<0><<<dim3(E2 / 128, BS / 128), blk, 0, stream>>>(
        xh, nullptr, w1h, nullptr, b1, nullptr, rope, qkv, nullptr, nullptr,
        E2, Ev, Ev);
    // GEMM2: q2/k2 from qkv (+SC on q) -> qkv2 [part][b][h][s][d];
    //        v2 = xh @ Wv2^T + bv2 -> v2t [b][h][d][s]
    gemm_f16<1><<<dim3(E3 / 128, BS / 128), blk, 0, stream>>>(
        qkv, xh, w1h, wv2, b1, bv2, nullptr, qkv2, v2t, nullptr, E3, Ev, E2);
    // flash attention -> ctx fp16
    attn_f16<<<dim3(Sv / 128, Hv, Bv), blk, 0, stream>>>(qkv2, v2t, ctx);
    // GEMM3: out = ctx @ wo^T + bo (fp32)
    gemm_f16<2><<<dim3(Ev / 128, BS / 128), blk, 0, stream>>>(
        ctx, nullptr, woh, nullptr, bo, nullptr, nullptr, nullptr, nullptr, out,
        Ev, Ev, Ev);
}

// Round 12
// 426.773 us; speedup vs baseline: 1.2535x; 1.2535x over previous
//
#include <hip/hip_runtime.h>
#include <math.h>

constexpr int Bv = 4, Sv = 2048, Ev = 1024, Hv = 16, Dv = 64;
constexpr int BS = Bv * Sv;     // 8192
constexpr int E3 = 3 * Ev;      // 3072
constexpr int E2 = 2 * Ev;      // 2048 (gemm1 output: q,k only; v collapsed)

typedef unsigned short ushort_t;
typedef _Float16 half8 __attribute__((ext_vector_type(8)));
typedef float floatx4 __attribute__((ext_vector_type(4)));

__device__ __forceinline__ floatx4 mfma16(half8 a, half8 b, floatx4 c) {
    return __builtin_amdgcn_mfma_f32_16x16x32_f16(a, b, c, 0, 0, 0);
}
__device__ __forceinline__ ushort_t f2h(float x) {
    _Float16 h = (_Float16)x;
    return *(ushort_t*)&h;
}
__device__ __forceinline__ unsigned pkrtz(float a, float b) {
    auto p = __builtin_amdgcn_cvt_pkrtz(a, b);
    return *(unsigned*)&p;
}
typedef const __attribute__((address_space(1))) unsigned int* gas_t;
typedef __attribute__((address_space(3))) unsigned int* las_t;
__device__ __forceinline__ void gl_lds16(const void* g, void* l) {
    __builtin_amdgcn_global_load_lds((gas_t)g, (las_t)l, 16, 0, 0);
}
// swizzled offset (ushort units) in a [rows][64]-half LDS tile; 16B-chunk xor
__device__ __forceinline__ int sw64(int row, int col) {
    return row * 64 + (((col >> 3) ^ (row & 7)) << 3) + (col & 7);
}
#define SOFTMAX_SC (0.125f * 1.44269504f)   // 1/sqrt(D) * log2(e), folded into q2

// ---------------------------------------------------------------------------
// Fused prep: all independent setup work in ONE dispatch, block-range switched.
// ---------------------------------------------------------------------------
constexpr int PS0 = 8192, PS1 = 11264, PS2 = 12288, PS3 = 12544,
              PS4 = 12800, PS5 = 13056;

__device__ __forceinline__ void conv_seg(const float* __restrict__ s,
                                         ushort_t* __restrict__ d, int i) {
    float4 v = ((const float4*)s)[i];
    ((ushort4*)d)[i] = make_ushort4(f2h(v.x), f2h(v.y), f2h(v.z), f2h(v.w));
}

__global__ __launch_bounds__(256)
void prep_k(const float* __restrict__ x, const float* __restrict__ w1,
            const float* __restrict__ b1,
            ushort_t* __restrict__ xh, ushort_t* __restrict__ w1h,
            ushort_t* __restrict__ woh, const float* __restrict__ wo,
            float* __restrict__ rope, ushort_t* __restrict__ wvt,
            float* __restrict__ bv2)
{
    __shared__ ushort_t t[64][65];
    const int blk = blockIdx.x, tid = threadIdx.x;
    if (blk < PS0) { conv_seg(x, xh, blk * 256 + tid); return; }
    if (blk < PS1) { conv_seg(w1, w1h, (blk - PS0) * 256 + tid); return; }
    if (blk < PS2) { conv_seg(wo, woh, (blk - PS1) * 256 + tid); return; }
    if (blk < PS3) {
        const int i = (blk - PS2) * 256 + tid;          // over S*32
        const int s = i >> 5, f = i & 31;
        const float fr = exp2f((float)f * -0.4152410118609203f);
        float sn, cs;
        sincosf((float)s * fr, &sn, &cs);
        ((float2*)rope)[i] = make_float2(cs, sn);
        return;
    }
    if (blk < PS4) {
        // Wv^T: w1 rows [2048,3072) fp32 -> wvt[k][n] fp16
        const int lin = blk - PS3;
        const int i0 = (lin >> 4) * 64, j0 = (lin & 15) * 64;
        #pragma unroll
        for (int p = 0; p < 16; ++p) {
            const int idx = p * 256 + tid;
            const int i = idx >> 6, j = idx & 63;       // read coalesced over j
            t[j][i] = f2h(w1[(size_t)(2048 + i0 + i) * 1024 + j0 + j]);
        }
        __syncthreads();
        #pragma unroll
        for (int p = 0; p < 16; ++p) {
            const int idx = p * 256 + tid;
            const int j = idx >> 6, i = idx & 63;       // write coalesced over i
            wvt[(size_t)(j0 + j) * 1024 + i0 + i] = t[j][i];
        }
        return;
    }
    {   // bv2[row] = bv[row] + sum_j Wv[row][j]*bv[j]
        const int row = (blk - PS4) * 4 + (tid >> 6);
        const int lane = tid & 63;
        const float* wr = w1 + (size_t)(2048 + row) * 1024;
        const float* bvp = b1 + 2048;
        float p = 0.f;
        for (int j = lane; j < 1024; j += 64) p += wr[j] * bvp[j];
        #pragma unroll
        for (int o = 32; o; o >>= 1) p += __shfl_down(p, o);
        if (lane == 0) bv2[row] = p + bvp[row];
    }
}

// ---------------------------------------------------------------------------
// wv2 = Wv @ Wv (fp16 in, fp32 accum, pkrtz out), 64x64 tiles, 256 blocks.
// ---------------------------------------------------------------------------
__global__ __launch_bounds__(256)
void wv2_k(const ushort_t* __restrict__ wv, const ushort_t* __restrict__ wvt,
           ushort_t* __restrict__ wv2)
{
    const int tid = threadIdx.x;
    const int lane = tid & 63, wid = tid >> 6;
    const int ln = lane & 15, quad = lane >> 4;
    const int r0 = blockIdx.y * 64 + wid * 16;   // output rows (this wave)
    const int c0 = blockIdx.x * 64;              // output cols

    const ushort_t* Ar = wv + (size_t)(r0 + ln) * 1024 + quad * 8;
    const ushort_t* Br = wvt + (size_t)(c0 + ln) * 1024 + quad * 8;

    const floatx4 Z = {0.f, 0.f, 0.f, 0.f};
    floatx4 acc[4] = {Z, Z, Z, Z};
    for (int k0 = 0; k0 < 1024; k0 += 32) {
        const half8 af = *(const half8*)(Ar + k0);
        #pragma unroll
        for (int nt = 0; nt < 4; ++nt) {
            const half8 bf = *(const half8*)(Br + (size_t)nt * 16 * 1024 + k0);
            acc[nt] = mfma16(bf, af, acc[nt]);
        }
    }
    #pragma unroll
    for (int nt = 0; nt < 4; ++nt) {
        uint2 o;
        o.x = pkrtz(acc[nt][0], acc[nt][1]);
        o.y = pkrtz(acc[nt][2], acc[nt][3]);
        *(uint2*)(wv2 + (size_t)(r0 + ln) * 1024 + c0 + nt * 16 + quad * 4) = o;
    }
}

// ---------------------------------------------------------------------------
// fp16 GEMM, C^T register layout (lane owns 4 consecutive n), fp32 accum.
// K-loop: 2-phase double-buffered staging (T3 minimum). Tile t+1's
// global_load_lds issued BEFORE tile t's ds_read+MFMA; ONE barrier per
// K-step (its vmcnt(0) drain lands after ~16 MFMA of overlap) instead of
// the old stage->barrier->compute->barrier (which exposed the full load
// latency at the first barrier every iteration). Es unions into the
// double-buffer region (dead after the final K-loop barrier): LDS 32KB.
// EPI 0: +bias, RoPE on q,k parts (table) -> qkv (B,S,E2) fp16, row stride N
// EPI 1: +bias (+SC on q) -> qkv2 [part][b][h][s][d] for q,k; v-part computed
//        from A2=xh with W2=Wv2 / bias2=bv2 -> outv [b][h][d][s]
// EPI 2: +bias -> fp32 outf (row stride N)
// ---------------------------------------------------------------------------
template<int EPI>
__global__ __launch_bounds__(256)
void gemm_f16(const ushort_t* __restrict__ A, const ushort_t* __restrict__ A2,
              const ushort_t* __restrict__ W, const ushort_t* __restrict__ W2,
              const float* __restrict__ bias, const float* __restrict__ bias2,
              const float* __restrict__ rope,
              ushort_t* __restrict__ outh, ushort_t* __restrict__ outv,
              float* __restrict__ outf, int N, int K, int lda)
{
    // 2 x (As 4096 + Bs 4096) ushorts = 32KB; Es (8704 ushorts) aliases the
    // front of the buffer space (safe: only touched after final K-loop barrier)
    __shared__ __align__(16) ushort_t smem[16384];
    ushort_t* const Es = smem;

    const int tid = threadIdx.x;
    const int lane = tid & 63, wid = tid >> 6;
    const int ln = lane & 15, quad = lane >> 4;
    const int n0 = blockIdx.x * 128, m0 = blockIdx.y * 128;
    const int wm = wid & 1, wn = wid >> 1;
    const int part = n0 >> 10;                         // 0=q 1=k 2=v

    // per-part operand selection (block-uniform)
    const ushort_t* Ap = A;  int ldaa = lda; int acol = 0;
    const ushort_t* Wp = W;
    const float* bp = bias;
    int nW = n0;                                       // row offset into Wp/bp
    if (EPI == 1) {
        if (part == 2) { Ap = A2; ldaa = Ev; Wp = W2; bp = bias2; nW = n0 - 2048; }
        else acol = part << 10;
    }

    const int f0 = wid * 1024 + lane * 8, f1 = f0 + 512;
    const int r0 = f0 >> 5, c0 = f0 & 31, r1 = f1 >> 5, c1 = f1 & 31;
    const size_t a0 = (size_t)(m0 + r0) * ldaa + acol + c0;
    const size_t a1 = (size_t)(m0 + r1) * ldaa + acol + c1;
    const size_t w0 = (size_t)(nW + r0) * K + c0;
    const size_t w1 = (size_t)(nW + r1) * K + c1;
    const int l0 = wid * 1024, l1 = wid * 1024 + 512;

    const floatx4 Z = {0.f, 0.f, 0.f, 0.f};
    floatx4 acc[4][4];
    #pragma unroll
    for (int i = 0; i < 4; ++i)
        #pragma unroll
        for (int j = 0; j < 4; ++j) acc[i][j] = Z;

    const int abase = (wm * 64 + ln) * 32 + quad * 8;
    const int bbase = (wn * 64 + ln) * 32 + quad * 8;

    // prologue: tile 0 into buffer 0
    {
        ushort_t* As = smem;
        ushort_t* Bs = smem + 4096;
        gl_lds16(Ap + a0, As + l0);
        gl_lds16(Ap + a1, As + l1);
        gl_lds16(Wp + w0, Bs + l0);
        gl_lds16(Wp + w1, Bs + l1);
    }
    __syncthreads();                      // tile 0 ready (only exposed wait)

    for (int k0 = 0; k0 < K; k0 += 32) {
        const int cur = (k0 >> 5) & 1;
        // issue tile k0+32 into the other buffer BEFORE computing tile k0:
        // its latency hides under the 16 MFMA below; drained at the barrier.
        if (k0 + 32 < K) {
            ushort_t* As = smem + (cur ^ 1) * 8192;
            ushort_t* Bs = As + 4096;
            gl_lds16(Ap + a0 + k0 + 32, As + l0);
            gl_lds16(Ap + a1 + k0 + 32, As + l1);
            gl_lds16(Wp + w0 + k0 + 32, Bs + l0);
            gl_lds16(Wp + w1 + k0 + 32, Bs + l1);
        }
        const ushort_t* As = smem + cur * 8192;
        const ushort_t* Bs = As + 4096;
        half8 af[4], bf[4];
        #pragma unroll
        for (int t = 0; t < 4; ++t) {
            af[t] = *(const half8*)(As + abase + t * 512);
            bf[t] = *(const half8*)(Bs + bbase + t * 512);
        }
        // C^T: acc[mt][nt] holds C[m = m0+wm*64+mt*16+ln][n = n0+wn*64+nt*16+quad*4+reg]
        #pragma unroll
        for (int mt = 0; mt < 4; ++mt)
            #pragma unroll
            for (int nt = 0; nt < 4; ++nt)
                acc[mt][nt] = mfma16(bf[nt], af[mt], acc[mt][nt]);
        __syncthreads();                  // next tile ready; buffer reusable
    }

    // bias: n depends on reg -> float4 per nt
    #pragma unroll
    for (int nt = 0; nt < 4; ++nt) {
        const float4 bb = *(const float4*)(bp + nW + wn * 64 + nt * 16 + quad * 4);
        #pragma unroll
        for (int mt = 0; mt < 4; ++mt) {
            acc[mt][nt][0] += bb.x; acc[mt][nt][1] += bb.y;
            acc[mt][nt][2] += bb.z; acc[mt][nt][3] += bb.w;
        }
    }

    if (EPI == 2) {
        #pragma unroll
        for (int mt = 0; mt < 4; ++mt)
            #pragma unroll
            for (int nt = 0; nt < 4; ++nt)
                *(floatx4*)(outf + (size_t)(m0 + wm * 64 + mt * 16 + ln) * N
                            + n0 + wn * 64 + nt * 16 + quad * 4) = acc[mt][nt];
        return;
    }

    // pack fp16 pairs (with RoPE / SC applied in-register)
    uint2 pk[4][4];
    if (EPI == 0 && part < 2) {
        // d = nt*16 + quad*4 + reg (mod 64); freq index = d&31; partner = nt^2
        #pragma unroll
        for (int mt = 0; mt < 4; ++mt) {
            const int s = (m0 + wm * 64 + mt * 16 + ln) & (Sv - 1);
            float sn[2][4], cs[2][4];
            #pragma unroll
            for (int p2 = 0; p2 < 2; ++p2) {
                const float* tb = rope + (size_t)(s * 32 + p2 * 16 + quad * 4) * 2;
                const float4 t0 = *(const float4*)(tb);
                const float4 t1 = *(const float4*)(tb + 4);
                cs[p2][0] = t0.x; sn[p2][0] = t0.y;
                cs[p2][1] = t0.z; sn[p2][1] = t0.w;
                cs[p2][2] = t1.x; sn[p2][2] = t1.y;
                cs[p2][3] = t1.z; sn[p2][3] = t1.w;
            }
            #pragma unroll
            for (int nt = 0; nt < 4; ++nt) {
                float v[4];
                #pragma unroll
                for (int reg = 0; reg < 4; ++reg) {
                    const float self = acc[mt][nt][reg];
                    const float partner = acc[mt][nt ^ 2][reg];
                    const float rot = (nt < 2) ? -partner : partner;
                    v[reg] = self * cs[nt & 1][reg] + rot * sn[nt & 1][reg];
                }
                pk[mt][nt].x = pkrtz(v[0], v[1]);
                pk[mt][nt].y = pkrtz(v[2], v[3]);
            }
        }
    } else {
        const float sc = (EPI == 1 && part == 0) ? SOFTMAX_SC : 1.0f;
        #pragma unroll
        for (int mt = 0; mt < 4; ++mt)
            #pragma unroll
            for (int nt = 0; nt < 4; ++nt) {
                pk[mt][nt].x = pkrtz(acc[mt][nt][0] * sc, acc[mt][nt][1] * sc);
                pk[mt][nt].y = pkrtz(acc[mt][nt][2] * sc, acc[mt][nt][3] * sc);
            }
    }

    // two passes (wm halves) through Es[64][136], then coalesced global stores
    for (int pass = 0; pass < 2; ++pass) {
        if (wm == pass) {
            #pragma unroll
            for (int mt = 0; mt < 4; ++mt)
                #pragma unroll
                for (int nt = 0; nt < 4; ++nt)
                    *(uint2*)(Es + (mt * 16 + ln) * 136 + wn * 64 + nt * 16 + quad * 4)
                        = pk[mt][nt];
        }
        __syncthreads();
        if (EPI == 0 || part < 2) {
            // each thread owns 32 halves = 4 x uint4 (uint4 = 8 ushorts)
            const int row = tid >> 2, coff = (tid & 3) * 32;
            uint4 u0 = *(const uint4*)(Es + row * 136 + coff);
            uint4 u1 = *(const uint4*)(Es + row * 136 + coff + 8);
            uint4 u2 = *(const uint4*)(Es + row * 136 + coff + 16);
            uint4 u3 = *(const uint4*)(Es + row * 136 + coff + 24);
            if (EPI == 0) {
                ushort_t* dst = outh + (size_t)(m0 + pass * 64 + row) * N + n0 + coff;
                *(uint4*)dst = u0; *(uint4*)(dst + 8) = u1;
                *(uint4*)(dst + 16) = u2; *(uint4*)(dst + 24) = u3;
            } else {
                const int b = m0 >> 11;
                const int s = (m0 & (Sv - 1)) + pass * 64 + row;
                const int h = ((n0 & (Ev - 1)) >> 6) + (coff >> 6);
                const int d0 = coff & 63;
                ushort_t* dst = outh + ((((size_t)part * Bv + b) * Hv + h) * Sv + s) * Dv + d0;
                *(uint4*)dst = u0; *(uint4*)(dst + 8) = u1;
                *(uint4*)(dst + 16) = u2; *(uint4*)(dst + 24) = u3;
            }
        } else {
            // v-part: transposed readback -> outv [b][h][d][s]
            const int dl = tid >> 1, sc0 = (tid & 1) * 32;
            ushort_t tmp[32];
            #pragma unroll
            for (int i = 0; i < 32; ++i) tmp[i] = Es[(sc0 + i) * 136 + dl];
            const int b = m0 >> 11;
            const int h = ((n0 & (Ev - 1)) >> 6) + (dl >> 6);
            const int d = dl & 63;
            ushort_t* dst = outv + (((size_t)b * Hv + h) * Dv + d) * Sv
                            + (m0 & (Sv - 1)) + pass * 64 + sc0;
            *(uint4*)dst = *(uint4*)&tmp[0];
            *(uint4*)(dst + 8) = *(uint4*)&tmp[8];
            *(uint4*)(dst + 16) = *(uint4*)&tmp[16];
            *(uint4*)(dst + 24) = *(uint4*)&tmp[24];
        }
        __syncthreads();
    }
}

// ---------------------------------------------------------------------------
// Flash attention (R4's proven 16x16 version, 129.6us): LDS staging + T14
// reg-prefetch + sw64 swizzle + raw-barrier publish/release, ORIGINAL grid
// mapping (q0 = bx*128, h = by, b = bz). Attn ledger R4-R11: 32x32 in-reg-P,
// V-permute, l-on-MFMA, XCD remap, barrier-free all measured >= this.
// ---------------------------------------------------------------------------
__global__ __launch_bounds__(256)
void attn_f16(const ushort_t* __restrict__ qkv2, const ushort_t* __restrict__ v2t,
              ushort_t* __restrict__ ctx)
{
    __shared__ __align__(16) ushort_t Ks[64 * 64];    // [key][d], swizzled
    __shared__ __align__(16) ushort_t Vts[64 * 64];   // [d][key], swizzled
    __shared__ __align__(16) ushort_t Ps[128 * 64];   // [q][key], swizzled

    const int tid = threadIdx.x;
    const int lane = tid & 63, wid = tid >> 6;
    const int ln = lane & 15, quad = lane >> 4;
    const int q0 = blockIdx.x * 128;
    const int h = blockIdx.y, b = blockIdx.z;
    const size_t plane = (size_t)Bv * Hv * Sv * Dv;
    const size_t hoff = ((size_t)b * Hv + h) * ((size_t)Sv * Dv);
    const ushort_t* Q = qkv2 + hoff;
    const ushort_t* Kp = qkv2 + plane + hoff;
    const ushort_t* Vt = v2t + ((size_t)b * Hv + h) * ((size_t)Dv * Sv);

    // Q fragments (B-operand) straight from global: B[n=ln -> q][k=quad*8+j -> d]
    half8 qa[2][2];
    #pragma unroll
    for (int qt = 0; qt < 2; ++qt)
        #pragma unroll
        for (int kh = 0; kh < 2; ++kh)
            qa[qt][kh] = *(const half8*)(Q + (size_t)(q0 + wid * 32 + qt * 16 + ln) * Dv
                                         + kh * 32 + quad * 8);

    // ones-row A fragment for l accumulation: A[m=ln][k] = (ln==0)
    half8 aones;
    #pragma unroll
    for (int j = 0; j < 8; ++j) aones[j] = (_Float16)(ln == 0 ? 1.0f : 0.0f);

    const floatx4 Z = {0.f, 0.f, 0.f, 0.f};
    floatx4 O[2][4], lacc[2];
    #pragma unroll
    for (int qt = 0; qt < 2; ++qt) {
        lacc[qt] = Z;
        #pragma unroll
        for (int dt = 0; dt < 4; ++dt) O[qt][dt] = Z;
    }

    const int kr = tid >> 2, kc = (tid & 3) * 16;
    const ushort_t* kptr = Kp + (size_t)kr * Dv + kc;
    const ushort_t* vptr = Vt + (size_t)kr * Sv + kc;

    // prologue: tile 0 into regs (only exposed latency of the whole loop)
    uint4 ka0 = *(const uint4*)(kptr);
    uint4 ka1 = *(const uint4*)(kptr + 8);
    uint4 va0 = *(const uint4*)(vptr);
    uint4 va1 = *(const uint4*)(vptr + 8);

    for (int kb = 0; kb < Sv; kb += 64) {
        // stage tile kb (regs -> LDS); previous iteration's tail barrier
        // guarantees all waves finished reading the buffer
        *(uint4*)(Ks + sw64(kr, kc)) = ka0;
        *(uint4*)(Ks + sw64(kr, kc + 8)) = ka1;
        *(uint4*)(Vts + sw64(kr, kc)) = va0;
        *(uint4*)(Vts + sw64(kr, kc + 8)) = va1;
        // issue tile kb+64's loads now: ~full tile of compute hides the latency
        if (kb + 64 < Sv) {
            const ushort_t* kn = kptr + (size_t)(kb + 64) * Dv;
            const ushort_t* vn = vptr + (kb + 64);
            ka0 = *(const uint4*)(kn);
            ka1 = *(const uint4*)(kn + 8);
            va0 = *(const uint4*)(vn);
            va1 = *(const uint4*)(vn + 8);
        }
        asm volatile("s_waitcnt lgkmcnt(0)" ::: "memory");  // own ds_writes done
        __builtin_amdgcn_s_barrier();                        // publish tile kb
        __builtin_amdgcn_sched_barrier(0);                   // no hoist past barrier

        // ---- S^T = K Q^T : st[kt][qt]; lane: key = kt*16+quad*4+reg, q-col = ln
        half8 kf[4][2];
        #pragma unroll
        for (int kt = 0; kt < 4; ++kt) {
            const int row = kt * 16 + ln;
            kf[kt][0] = *(const half8*)(Ks + sw64(row, quad * 8));
            kf[kt][1] = *(const half8*)(Ks + sw64(row, 32 + quad * 8));
        }
        floatx4 st[4][2];
        #pragma unroll
        for (int kt = 0; kt < 4; ++kt)
            #pragma unroll
            for (int qt = 0; qt < 2; ++qt) {
                st[kt][qt] = mfma16(kf[kt][0], qa[qt][0], Z);
                st[kt][qt] = mfma16(kf[kt][1], qa[qt][1], st[kt][qt]);
            }

        // ---- p = exp2(s), pack, store P[q][key] (wave-private rows, no barrier)
        #pragma unroll
        for (int qt = 0; qt < 2; ++qt) {
            const int q = wid * 32 + qt * 16 + ln;
            #pragma unroll
            for (int kt = 0; kt < 4; ++kt) {
                uint2 pkv;
                pkv.x = pkrtz(exp2f(st[kt][qt][0]), exp2f(st[kt][qt][1]));
                pkv.y = pkrtz(exp2f(st[kt][qt][2]), exp2f(st[kt][qt][3]));
                *(uint2*)(Ps + sw64(q, kt * 16 + quad * 4)) = pkv;
            }
        }

        // ---- O^T += V^T P^T ; l += ones-row . P ----
        half8 va[4][2];
        #pragma unroll
        for (int dt = 0; dt < 4; ++dt) {
            const int row = dt * 16 + ln;
            va[dt][0] = *(const half8*)(Vts + sw64(row, quad * 8));
            va[dt][1] = *(const half8*)(Vts + sw64(row, 32 + quad * 8));
        }
        #pragma unroll
        for (int qt = 0; qt < 2; ++qt) {
            const int q = wid * 32 + qt * 16 + ln;
            half8 pb0 = *(const half8*)(Ps + sw64(q, quad * 8));
            half8 pb1 = *(const half8*)(Ps + sw64(q, 32 + quad * 8));
            #pragma unroll
            for (int dt = 0; dt < 4; ++dt) {
                O[qt][dt] = mfma16(va[dt][0], pb0, O[qt][dt]);
                O[qt][dt] = mfma16(va[dt][1], pb1, O[qt][dt]);
            }
            lacc[qt] = mfma16(aones, pb0, lacc[qt]);
            lacc[qt] = mfma16(aones, pb1, lacc[qt]);
        }

        __builtin_amdgcn_sched_barrier(0);
        __builtin_amdgcn_s_barrier();                        // release tile kb
        __builtin_amdgcn_sched_barrier(0);                   // next ds_write stays below
    }

    // epilogue: l lives in D[0][q] = lanes 0..15 (quad 0, reg 0); broadcast
    #pragma unroll
    for (int qt = 0; qt < 2; ++qt) {
        const float lq = __shfl(lacc[qt][0], ln);
        const float il = 1.0f / lq;
        const int q = q0 + wid * 32 + qt * 16 + ln;
        #pragma unroll
        for (int dt = 0; dt < 4; ++dt) {
            uint2 ov;
            ov.x = pkrtz(O[qt][dt][0] * il, O[qt][dt][1] * il);
            ov.y = pkrtz(O[qt][dt][2] * il, O[qt][dt][3] * il);
            *(uint2*)(ctx + ((size_t)(b * Sv + q)) * Ev + h * Dv + dt * 16 + quad * 4) = ov;
        }
    }
}

// ---------------------------------------------------------------------------
extern "C" void kernel_launch(void* const* d_in, const int* in_sizes, int n_in,
                              void* d_out, int out_size, void* d_ws, size_t ws_size,
                              hipStream_t stream) {
    const float* x  = (const float*)d_in[0];
    const float* w1 = (const float*)d_in[1];
    const float* b1 = (const float*)d_in[2];
    const float* wo = (const float*)d_in[3];
    const float* bo = (const float*)d_in[4];
    float* out = (float*)d_out;

    char* w = (char*)d_ws;
    ushort_t* xh   = (ushort_t*)(w + 0);            // 16,777,216
    ushort_t* w1h  = (ushort_t*)(w + 16777216);     //  6,291,456
    ushort_t* woh  = (ushort_t*)(w + 23068672);     //  2,097,152
    ushort_t* qkv  = (ushort_t*)(w + 25165824);     // 33,554,432 (B,S,E2): q,k only
    ushort_t* qkv2 = (ushort_t*)(w + 75497472);     // [2][b][h][s][d] used (32MB)
    ushort_t* v2t  = (ushort_t*)(w + 125829120);    // 16,777,216 [b][h][d][s]
    ushort_t* ctx  = (ushort_t*)(w + 142606336);    // 16,777,216 (B,S,E)
    float* rope = (float*)(w + 75497472);           // 512 KB, dead before gemm2
    ushort_t* wvt = (ushort_t*)(w + 75497472 + 33554432);             // 2MB
    ushort_t* wv2 = (ushort_t*)(w + 75497472 + 33554432 + 2097152);   // 2MB
    float*    bv2 = (float*)   (w + 75497472 + 33554432 + 4194304);   // 4KB

    dim3 blk(256);
    // fused prep: convs + rope table + Wv^T + bv2, one dispatch
    prep_k<<<dim3(PS5), blk, 0, stream>>>(x, w1, b1, xh, w1h, woh, wo,
                                          rope, wvt, bv2);
    // Wv2 = Wv @ Wv
    wv2_k<<<dim3(16, 16), blk, 0, stream>>>(w1h + (size_t)2048 * 1024, wvt, wv2);

    // GEMM1 + bias + RoPE (table) -> qkv (B,S,E2) fp16  (q,k only; v collapsed)
    gemm_f16<0><<<dim3(E2 / 128, BS / 128), blk, 0, stream>>>(
        xh, nullptr, w1h, nullptr, b1, nullptr, rope, qkv, nullptr, nullptr,
        E2, Ev, Ev);
    // GEMM2: q2/k2 from qkv (+SC on q) -> qkv2 [part][b][h][s][d];
    //        v2 = xh @ Wv2^T + bv2 -> v2t [b][h][d][s]
    gemm_f16<1><<<dim3(E3 / 128, BS / 128), blk, 0, stream>>>(
        qkv, xh, w1h, wv2, b1, bv2, nullptr, qkv2, v2t, nullptr, E3, Ev, E2);
    // flash attention -> ctx fp16
    attn_f16<<<dim3(Sv / 128, Hv, Bv), blk, 0, stream>>>(qkv2, v2t, ctx);
    // GEMM3: out = ctx @ wo^T + bo (fp32)
    gemm_f16<2><<<dim3(Ev / 128, BS / 128), blk, 0, stream>>>(
        ctx, nullptr, woh, nullptr, bo, nullptr, nullptr, nullptr, nullptr, out,
        Ev, Ev, Ev);
}

// Round 13
// 395.449 us; speedup vs baseline: 1.3528x; 1.0792x over previous
//
#include <hip/hip_runtime.h>
#include <math.h>

constexpr int Bv = 4, Sv = 2048, Ev = 1024, Hv = 16, Dv = 64;
constexpr int BS = Bv * Sv;     // 8192
constexpr int E3 = 3 * Ev;      // 3072
constexpr int E2 = 2 * Ev;      // 2048 (gemm1 output: q,k only; v collapsed)

typedef unsigned short ushort_t;
typedef _Float16 half8 __attribute__((ext_vector_type(8)));
typedef float floatx4 __attribute__((ext_vector_type(4)));

__device__ __forceinline__ floatx4 mfma16(half8 a, half8 b, floatx4 c) {
    return __builtin_amdgcn_mfma_f32_16x16x32_f16(a, b, c, 0, 0, 0);
}
__device__ __forceinline__ ushort_t f2h(float x) {
    _Float16 h = (_Float16)x;
    return *(ushort_t*)&h;
}
__device__ __forceinline__ unsigned pkrtz(float a, float b) {
    auto p = __builtin_amdgcn_cvt_pkrtz(a, b);
    return *(unsigned*)&p;
}
typedef const __attribute__((address_space(1))) unsigned int* gas_t;
typedef __attribute__((address_space(3))) unsigned int* las_t;
__device__ __forceinline__ void gl_lds16(const void* g, void* l) {
    __builtin_amdgcn_global_load_lds((gas_t)g, (las_t)l, 16, 0, 0);
}
// swizzled offset (ushort units) in a [rows][64]-half LDS tile; 16B-chunk xor
__device__ __forceinline__ int sw64(int row, int col) {
    return row * 64 + (((col >> 3) ^ (row & 7)) << 3) + (col & 7);
}
#define SOFTMAX_SC (0.125f * 1.44269504f)   // 1/sqrt(D) * log2(e), folded into q2

// ---------------------------------------------------------------------------
// Fused prep: all independent setup work in ONE dispatch, block-range switched.
// ---------------------------------------------------------------------------
constexpr int PS0 = 8192, PS1 = 11264, PS2 = 12288, PS3 = 12544,
              PS4 = 12800, PS5 = 13056;

__device__ __forceinline__ void conv_seg(const float* __restrict__ s,
                                         ushort_t* __restrict__ d, int i) {
    float4 v = ((const float4*)s)[i];
    ((ushort4*)d)[i] = make_ushort4(f2h(v.x), f2h(v.y), f2h(v.z), f2h(v.w));
}

__global__ __launch_bounds__(256)
void prep_k(const float* __restrict__ x, const float* __restrict__ w1,
            const float* __restrict__ b1,
            ushort_t* __restrict__ xh, ushort_t* __restrict__ w1h,
            ushort_t* __restrict__ woh, const float* __restrict__ wo,
            float* __restrict__ rope, ushort_t* __restrict__ wvt,
            float* __restrict__ bv2)
{
    __shared__ ushort_t t[64][65];
    const int blk = blockIdx.x, tid = threadIdx.x;
    if (blk < PS0) { conv_seg(x, xh, blk * 256 + tid); return; }
    if (blk < PS1) { conv_seg(w1, w1h, (blk - PS0) * 256 + tid); return; }
    if (blk < PS2) { conv_seg(wo, woh, (blk - PS1) * 256 + tid); return; }
    if (blk < PS3) {
        const int i = (blk - PS2) * 256 + tid;          // over S*32
        const int s = i >> 5, f = i & 31;
        const float fr = exp2f((float)f * -0.4152410118609203f);
        float sn, cs;
        sincosf((float)s * fr, &sn, &cs);
        ((float2*)rope)[i] = make_float2(cs, sn);
        return;
    }
    if (blk < PS4) {
        // Wv^T: w1 rows [2048,3072) fp32 -> wvt[k][n] fp16
        const int lin = blk - PS3;
        const int i0 = (lin >> 4) * 64, j0 = (lin & 15) * 64;
        #pragma unroll
        for (int p = 0; p < 16; ++p) {
            const int idx = p * 256 + tid;
            const int i = idx >> 6, j = idx & 63;       // read coalesced over j
            t[j][i] = f2h(w1[(size_t)(2048 + i0 + i) * 1024 + j0 + j]);
        }
        __syncthreads();
        #pragma unroll
        for (int p = 0; p < 16; ++p) {
            const int idx = p * 256 + tid;
            const int j = idx >> 6, i = idx & 63;       // write coalesced over i
            wvt[(size_t)(j0 + j) * 1024 + i0 + i] = t[j][i];
        }
        return;
    }
    {   // bv2[row] = bv[row] + sum_j Wv[row][j]*bv[j]
        const int row = (blk - PS4) * 4 + (tid >> 6);
        const int lane = tid & 63;
        const float* wr = w1 + (size_t)(2048 + row) * 1024;
        const float* bvp = b1 + 2048;
        float p = 0.f;
        for (int j = lane; j < 1024; j += 64) p += wr[j] * bvp[j];
        #pragma unroll
        for (int o = 32; o; o >>= 1) p += __shfl_down(p, o);
        if (lane == 0) bv2[row] = p + bvp[row];
    }
}

// ---------------------------------------------------------------------------
// wv2 = Wv @ Wv (fp16 in, fp32 accum, pkrtz out), 64x64 tiles, 256 blocks.
// ---------------------------------------------------------------------------
__global__ __launch_bounds__(256)
void wv2_k(const ushort_t* __restrict__ wv, const ushort_t* __restrict__ wvt,
           ushort_t* __restrict__ wv2)
{
    const int tid = threadIdx.x;
    const int lane = tid & 63, wid = tid >> 6;
    const int ln = lane & 15, quad = lane >> 4;
    const int r0 = blockIdx.y * 64 + wid * 16;   // output rows (this wave)
    const int c0 = blockIdx.x * 64;              // output cols

    const ushort_t* Ar = wv + (size_t)(r0 + ln) * 1024 + quad * 8;
    const ushort_t* Br = wvt + (size_t)(c0 + ln) * 1024 + quad * 8;

    const floatx4 Z = {0.f, 0.f, 0.f, 0.f};
    floatx4 acc[4] = {Z, Z, Z, Z};
    for (int k0 = 0; k0 < 1024; k0 += 32) {
        const half8 af = *(const half8*)(Ar + k0);
        #pragma unroll
        for (int nt = 0; nt < 4; ++nt) {
            const half8 bf = *(const half8*)(Br + (size_t)nt * 16 * 1024 + k0);
            acc[nt] = mfma16(bf, af, acc[nt]);
        }
    }
    #pragma unroll
    for (int nt = 0; nt < 4; ++nt) {
        uint2 o;
        o.x = pkrtz(acc[nt][0], acc[nt][1]);
        o.y = pkrtz(acc[nt][2], acc[nt][3]);
        *(uint2*)(wv2 + (size_t)(r0 + ln) * 1024 + c0 + nt * 16 + quad * 4) = o;
    }
}

// ---------------------------------------------------------------------------
// fp16 GEMM, C^T register layout, fp32 accum. BK=64 K-steps (16 iters vs 32:
// HALF the barrier drains, each amortized over 32 MFMA) with T21 both-sides
// swizzle: LDS stays LINEAR [128][64] for global_load_lds (wave-uniform +
// lane*16B preserved); the GLOBAL source column is chunk-XOR'd (involution,
// stays within the 128B row -> coalescing kept); fragment reads use sw64 ->
// ~2-way bank conflicts (free) instead of naive 16-way at 128B row stride.
// MFMA order per acc cell is k-ascending as before -> bit-identical results.
// Es aliases the staging buffers (dead after final K-loop barrier; R12-proven).
// EPI 0: +bias, RoPE on q,k parts (table) -> qkv (B,S,E2) fp16, row stride N
// EPI 1: +bias (+SC on q) -> qkv2 [part][b][h][s][d] for q,k; v-part from
//        A2=xh with W2=Wv2 / bias2=bv2 -> outv [b][h][d][s]
// EPI 2: +bias -> fp32 outf (row stride N)
// ---------------------------------------------------------------------------
template<int EPI>
__global__ __launch_bounds__(256)
void gemm_f16(const ushort_t* __restrict__ A, const ushort_t* __restrict__ A2,
              const ushort_t* __restrict__ W, const ushort_t* __restrict__ W2,
              const float* __restrict__ bias, const float* __restrict__ bias2,
              const float* __restrict__ rope,
              ushort_t* __restrict__ outh, ushort_t* __restrict__ outv,
              float* __restrict__ outf, int N, int K, int lda)
{
    // As [128][64] + Bs [128][64] halves = 32KB; Es (8704 halves) aliases.
    __shared__ __align__(16) ushort_t smem[16384];
    ushort_t* const As = smem;
    ushort_t* const Bs = smem + 8192;
    ushort_t* const Es = smem;

    const int tid = threadIdx.x;
    const int lane = tid & 63, wid = tid >> 6;
    const int ln = lane & 15, quad = lane >> 4;
    const int n0 = blockIdx.x * 128, m0 = blockIdx.y * 128;
    const int wm = wid & 1, wn = wid >> 1;
    const int part = n0 >> 10;                         // 0=q 1=k 2=v

    // per-part operand selection (block-uniform)
    const ushort_t* Ap = A;  int ldaa = lda; int acol = 0;
    const ushort_t* Wp = W;
    const float* bp = bias;
    int nW = n0;                                       // row offset into Wp/bp
    if (EPI == 1) {
        if (part == 2) { Ap = A2; ldaa = Ev; Wp = W2; bp = bias2; nW = n0 - 2048; }
        else acol = part << 10;
    }

    // staging: 4 chunks/thread/matrix; LDS dest LINEAR e, global col inverse-
    // swizzled (involution): cg = ((c>>3)^(r&7))<<3  (c&7==0 always)
    int srow[4], scol[4], sdst[4];
    #pragma unroll
    for (int i = 0; i < 4; ++i) {
        const int e = i * 2048 + tid * 8;
        const int r = e >> 6, c = e & 63;
        srow[i] = r;
        scol[i] = (((c >> 3) ^ (r & 7)) << 3);
        sdst[i] = e;
    }

    const floatx4 Z = {0.f, 0.f, 0.f, 0.f};
    floatx4 acc[4][4];
    #pragma unroll
    for (int i = 0; i < 4; ++i)
        #pragma unroll
        for (int j = 0; j < 4; ++j) acc[i][j] = Z;

    for (int k0 = 0; k0 < K; k0 += 64) {
        #pragma unroll
        for (int i = 0; i < 4; ++i) {
            gl_lds16(Ap + (size_t)(m0 + srow[i]) * ldaa + acol + k0 + scol[i],
                     As + sdst[i]);
            gl_lds16(Wp + (size_t)(nW + srow[i]) * K + k0 + scol[i],
                     Bs + sdst[i]);
        }
        __syncthreads();
        // two K=32 halves, k-ascending (same accumulate order as BK=32 version)
        #pragma unroll
        for (int kh = 0; kh < 2; ++kh) {
            half8 af[4], bf[4];
            #pragma unroll
            for (int t = 0; t < 4; ++t) {
                af[t] = *(const half8*)(As + sw64(wm * 64 + t * 16 + ln,
                                                  kh * 32 + quad * 8));
                bf[t] = *(const half8*)(Bs + sw64(wn * 64 + t * 16 + ln,
                                                  kh * 32 + quad * 8));
            }
            // C^T: acc[mt][nt] = C[m0+wm*64+mt*16+ln][n0+wn*64+nt*16+quad*4+reg]
            #pragma unroll
            for (int mt = 0; mt < 4; ++mt)
                #pragma unroll
                for (int nt = 0; nt < 4; ++nt)
                    acc[mt][nt] = mfma16(bf[nt], af[mt], acc[mt][nt]);
        }
        __syncthreads();
    }

    // bias: n depends on reg -> float4 per nt
    #pragma unroll
    for (int nt = 0; nt < 4; ++nt) {
        const float4 bb = *(const float4*)(bp + nW + wn * 64 + nt * 16 + quad * 4);
        #pragma unroll
        for (int mt = 0; mt < 4; ++mt) {
            acc[mt][nt][0] += bb.x; acc[mt][nt][1] += bb.y;
            acc[mt][nt][2] += bb.z; acc[mt][nt][3] += bb.w;
        }
    }

    if (EPI == 2) {
        #pragma unroll
        for (int mt = 0; mt < 4; ++mt)
            #pragma unroll
            for (int nt = 0; nt < 4; ++nt)
                *(floatx4*)(outf + (size_t)(m0 + wm * 64 + mt * 16 + ln) * N
                            + n0 + wn * 64 + nt * 16 + quad * 4) = acc[mt][nt];
        return;
    }

    // pack fp16 pairs (with RoPE / SC applied in-register)
    uint2 pk[4][4];
    if (EPI == 0 && part < 2) {
        // d = nt*16 + quad*4 + reg (mod 64); freq index = d&31; partner = nt^2
        #pragma unroll
        for (int mt = 0; mt < 4; ++mt) {
            const int s = (m0 + wm * 64 + mt * 16 + ln) & (Sv - 1);
            float sn[2][4], cs[2][4];
            #pragma unroll
            for (int p2 = 0; p2 < 2; ++p2) {
                const float* tb = rope + (size_t)(s * 32 + p2 * 16 + quad * 4) * 2;
                const float4 t0 = *(const float4*)(tb);
                const float4 t1 = *(const float4*)(tb + 4);
                cs[p2][0] = t0.x; sn[p2][0] = t0.y;
                cs[p2][1] = t0.z; sn[p2][1] = t0.w;
                cs[p2][2] = t1.x; sn[p2][2] = t1.y;
                cs[p2][3] = t1.z; sn[p2][3] = t1.w;
            }
            #pragma unroll
            for (int nt = 0; nt < 4; ++nt) {
                float v[4];
                #pragma unroll
                for (int reg = 0; reg < 4; ++reg) {
                    const float self = acc[mt][nt][reg];
                    const float partner = acc[mt][nt ^ 2][reg];
                    const float rot = (nt < 2) ? -partner : partner;
                    v[reg] = self * cs[nt & 1][reg] + rot * sn[nt & 1][reg];
                }
                pk[mt][nt].x = pkrtz(v[0], v[1]);
                pk[mt][nt].y = pkrtz(v[2], v[3]);
            }
        }
    } else {
        const float sc = (EPI == 1 && part == 0) ? SOFTMAX_SC : 1.0f;
        #pragma unroll
        for (int mt = 0; mt < 4; ++mt)
            #pragma unroll
            for (int nt = 0; nt < 4; ++nt) {
                pk[mt][nt].x = pkrtz(acc[mt][nt][0] * sc, acc[mt][nt][1] * sc);
                pk[mt][nt].y = pkrtz(acc[mt][nt][2] * sc, acc[mt][nt][3] * sc);
            }
    }

    // two passes (wm halves) through Es[64][136], then coalesced global stores
    for (int pass = 0; pass < 2; ++pass) {
        if (wm == pass) {
            #pragma unroll
            for (int mt = 0; mt < 4; ++mt)
                #pragma unroll
                for (int nt = 0; nt < 4; ++nt)
                    *(uint2*)(Es + (mt * 16 + ln) * 136 + wn * 64 + nt * 16 + quad * 4)
                        = pk[mt][nt];
        }
        __syncthreads();
        if (EPI == 0 || part < 2) {
            // each thread owns 32 halves = 4 x uint4 (uint4 = 8 ushorts)
            const int row = tid >> 2, coff = (tid & 3) * 32;
            uint4 u0 = *(const uint4*)(Es + row * 136 + coff);
            uint4 u1 = *(const uint4*)(Es + row * 136 + coff + 8);
            uint4 u2 = *(const uint4*)(Es + row * 136 + coff + 16);
            uint4 u3 = *(const uint4*)(Es + row * 136 + coff + 24);
            if (EPI == 0) {
                ushort_t* dst = outh + (size_t)(m0 + pass * 64 + row) * N + n0 + coff;
                *(uint4*)dst = u0; *(uint4*)(dst + 8) = u1;
                *(uint4*)(dst + 16) = u2; *(uint4*)(dst + 24) = u3;
            } else {
                const int b = m0 >> 11;
                const int s = (m0 & (Sv - 1)) + pass * 64 + row;
                const int h = ((n0 & (Ev - 1)) >> 6) + (coff >> 6);
                const int d0 = coff & 63;
                ushort_t* dst = outh + ((((size_t)part * Bv + b) * Hv + h) * Sv + s) * Dv + d0;
                *(uint4*)dst = u0; *(uint4*)(dst + 8) = u1;
                *(uint4*)(dst + 16) = u2; *(uint4*)(dst + 24) = u3;
            }
        } else {
            // v-part: transposed readback -> outv [b][h][d][s]
            const int dl = tid >> 1, sc0 = (tid & 1) * 32;
            ushort_t tmp[32];
            #pragma unroll
            for (int i = 0; i < 32; ++i) tmp[i] = Es[(sc0 + i) * 136 + dl];
            const int b = m0 >> 11;
            const int h = ((n0 & (Ev - 1)) >> 6) + (dl >> 6);
            const int d = dl & 63;
            ushort_t* dst = outv + (((size_t)b * Hv + h) * Dv + d) * Sv
                            + (m0 & (Sv - 1)) + pass * 64 + sc0;
            *(uint4*)dst = *(uint4*)&tmp[0];
            *(uint4*)(dst + 8) = *(uint4*)&tmp[8];
            *(uint4*)(dst + 16) = *(uint4*)&tmp[16];
            *(uint4*)(dst + 24) = *(uint4*)&tmp[24];
        }
        __syncthreads();
    }
}

// ---------------------------------------------------------------------------
// Flash attention (R4's proven 16x16 version, 129.6us): LDS staging + T14
// reg-prefetch + sw64 swizzle + raw-barrier publish/release, original grid.
// Attn ledger R4-R11: all structural variants measured >= this; converged.
// ---------------------------------------------------------------------------
__global__ __launch_bounds__(256)
void attn_f16(const ushort_t* __restrict__ qkv2, const ushort_t* __restrict__ v2t,
              ushort_t* __restrict__ ctx)
{
    __shared__ __align__(16) ushort_t Ks[64 * 64];    // [key][d], swizzled
    __shared__ __align__(16) ushort_t Vts[64 * 64];   // [d][key], swizzled
    __shared__ __align__(16) ushort_t Ps[128 * 64];   // [q][key], swizzled

    const int tid = threadIdx.x;
    const int lane = tid & 63, wid = tid >> 6;
    const int ln = lane & 15, quad = lane >> 4;
    const int q0 = blockIdx.x * 128;
    const int h = blockIdx.y, b = blockIdx.z;
    const size_t plane = (size_t)Bv * Hv * Sv * Dv;
    const size_t hoff = ((size_t)b * Hv + h) * ((size_t)Sv * Dv);
    const ushort_t* Q = qkv2 + hoff;
    const ushort_t* Kp = qkv2 + plane + hoff;
    const ushort_t* Vt = v2t + ((size_t)b * Hv + h) * ((size_t)Dv * Sv);

    // Q fragments (B-operand) straight from global: B[n=ln -> q][k=quad*8+j -> d]
    half8 qa[2][2];
    #pragma unroll
    for (int qt = 0; qt < 2; ++qt)
        #pragma unroll
        for (int kh = 0; kh < 2; ++kh)
            qa[qt][kh] = *(const half8*)(Q + (size_t)(q0 + wid * 32 + qt * 16 + ln) * Dv
                                         + kh * 32 + quad * 8);

    // ones-row A fragment for l accumulation: A[m=ln][k] = (ln==0)
    half8 aones;
    #pragma unroll
    for (int j = 0; j < 8; ++j) aones[j] = (_Float16)(ln == 0 ? 1.0f : 0.0f);

    const floatx4 Z = {0.f, 0.f, 0.f, 0.f};
    floatx4 O[2][4], lacc[2];
    #pragma unroll
    for (int qt = 0; qt < 2; ++qt) {
        lacc[qt] = Z;
        #pragma unroll
        for (int dt = 0; dt < 4; ++dt) O[qt][dt] = Z;
    }

    const int kr = tid >> 2, kc = (tid & 3) * 16;
    const ushort_t* kptr = Kp + (size_t)kr * Dv + kc;
    const ushort_t* vptr = Vt + (size_t)kr * Sv + kc;

    // prologue: tile 0 into regs (only exposed latency of the whole loop)
    uint4 ka0 = *(const uint4*)(kptr);
    uint4 ka1 = *(const uint4*)(kptr + 8);
    uint4 va0 = *(const uint4*)(vptr);
    uint4 va1 = *(const uint4*)(vptr + 8);

    for (int kb = 0; kb < Sv; kb += 64) {
        // stage tile kb (regs -> LDS); previous iteration's tail barrier
        // guarantees all waves finished reading the buffer
        *(uint4*)(Ks + sw64(kr, kc)) = ka0;
        *(uint4*)(Ks + sw64(kr, kc + 8)) = ka1;
        *(uint4*)(Vts + sw64(kr, kc)) = va0;
        *(uint4*)(Vts + sw64(kr, kc + 8)) = va1;
        // issue tile kb+64's loads now: ~full tile of compute hides the latency
        if (kb + 64 < Sv) {
            const ushort_t* kn = kptr + (size_t)(kb + 64) * Dv;
            const ushort_t* vn = vptr + (kb + 64);
            ka0 = *(const uint4*)(kn);
            ka1 = *(const uint4*)(kn + 8);
            va0 = *(const uint4*)(vn);
            va1 = *(const uint4*)(vn + 8);
        }
        asm volatile("s_waitcnt lgkmcnt(0)" ::: "memory");  // own ds_writes done
        __builtin_amdgcn_s_barrier();                        // publish tile kb
        __builtin_amdgcn_sched_barrier(0);                   // no hoist past barrier

        // ---- S^T = K Q^T : st[kt][qt]; lane: key = kt*16+quad*4+reg, q-col = ln
        half8 kf[4][2];
        #pragma unroll
        for (int kt = 0; kt < 4; ++kt) {
            const int row = kt * 16 + ln;
            kf[kt][0] = *(const half8*)(Ks + sw64(row, quad * 8));
            kf[kt][1] = *(const half8*)(Ks + sw64(row, 32 + quad * 8));
        }
        floatx4 st[4][2];
        #pragma unroll
        for (int kt = 0; kt < 4; ++kt)
            #pragma unroll
            for (int qt = 0; qt < 2; ++qt) {
                st[kt][qt] = mfma16(kf[kt][0], qa[qt][0], Z);
                st[kt][qt] = mfma16(kf[kt][1], qa[qt][1], st[kt][qt]);
            }

        // ---- p = exp2(s), pack, store P[q][key] (wave-private rows, no barrier)
        #pragma unroll
        for (int qt = 0; qt < 2; ++qt) {
            const int q = wid * 32 + qt * 16 + ln;
            #pragma unroll
            for (int kt = 0; kt < 4; ++kt) {
                uint2 pkv;
                pkv.x = pkrtz(exp2f(st[kt][qt][0]), exp2f(st[kt][qt][1]));
                pkv.y = pkrtz(exp2f(st[kt][qt][2]), exp2f(st[kt][qt][3]));
                *(uint2*)(Ps + sw64(q, kt * 16 + quad * 4)) = pkv;
            }
        }

        // ---- O^T += V^T P^T ; l += ones-row . P ----
        half8 va[4][2];
        #pragma unroll
        for (int dt = 0; dt < 4; ++dt) {
            const int row = dt * 16 + ln;
            va[dt][0] = *(const half8*)(Vts + sw64(row, quad * 8));
            va[dt][1] = *(const half8*)(Vts + sw64(row, 32 + quad * 8));
        }
        #pragma unroll
        for (int qt = 0; qt < 2; ++qt) {
            const int q = wid * 32 + qt * 16 + ln;
            half8 pb0 = *(const half8*)(Ps + sw64(q, quad * 8));
            half8 pb1 = *(const half8*)(Ps + sw64(q, 32 + quad * 8));
            #pragma unroll
            for (int dt = 0; dt < 4; ++dt) {
                O[qt][dt] = mfma16(va[dt][0], pb0, O[qt][dt]);
                O[qt][dt] = mfma16(va[dt][1], pb1, O[qt][dt]);
            }
            lacc[qt] = mfma16(aones, pb0, lacc[qt]);
            lacc[qt] = mfma16(aones, pb1, lacc[qt]);
        }

        __builtin_amdgcn_sched_barrier(0);
        __builtin_amdgcn_s_barrier();                        // release tile kb
        __builtin_amdgcn_sched_barrier(0);                   // next ds_write stays below
    }

    // epilogue: l lives in D[0][q] = lanes 0..15 (quad 0, reg 0); broadcast
    #pragma unroll
    for (int qt = 0; qt < 2; ++qt) {
        const float lq = __shfl(lacc[qt][0], ln);
        const float il = 1.0f / lq;
        const int q = q0 + wid * 32 + qt * 16 + ln;
        #pragma unroll
        for (int dt = 0; dt < 4; ++dt) {
            uint2 ov;
            ov.x = pkrtz(O[qt][dt][0] * il, O[qt][dt][1] * il);
            ov.y = pkrtz(O[qt][dt][2] * il, O[qt][dt][3] * il);
            *(uint2*)(ctx + ((size_t)(b * Sv + q)) * Ev + h * Dv + dt * 16 + quad * 4) = ov;
        }
    }
}

// ---------------------------------------------------------------------------
extern "C" void kernel_launch(void* const* d_in, const int* in_sizes, int n_in,
                              void* d_out, int out_size, void* d_ws, size_t ws_size,
                              hipStream_t stream) {
    const float* x  = (const float*)d_in[0];
    const float* w1 = (const float*)d_in[1];
    const float* b1 = (const float*)d_in[2];
    const float* wo = (const float*)d_in[3];
    const float* bo = (const float*)d_in[4];
    float* out = (float*)d_out;

    char* w = (char*)d_ws;
    ushort_t* xh   = (ushort_t*)(w + 0);            // 16,777,216
    ushort_t* w1h  = (ushort_t*)(w + 16777216);     //  6,291,456
    ushort_t* woh  = (ushort_t*)(w + 23068672);     //  2,097,152
    ushort_t* qkv  = (ushort_t*)(w + 25165824);     // 33,554,432 (B,S,E2): q,k only
    ushort_t* qkv2 = (ushort_t*)(w + 75497472);     // [2][b][h][s][d] used (32MB)
    ushort_t* v2t  = (ushort_t*)(w + 125829120);    // 16,777,216 [b][h][d][s]
    ushort_t* ctx  = (ushort_t*)(w + 142606336);    // 16,777,216 (B,S,E)
    float* rope = (float*)(w + 75497472);           // 512 KB, dead before gemm2
    ushort_t* wvt = (ushort_t*)(w + 75497472 + 33554432);             // 2MB
    ushort_t* wv2 = (ushort_t*)(w + 75497472 + 33554432 + 2097152);   // 2MB
    float*    bv2 = (float*)   (w + 75497472 + 33554432 + 4194304);   // 4KB

    dim3 blk(256);
    // fused prep: convs + rope table + Wv^T + bv2, one dispatch
    prep_k<<<dim3(PS5), blk, 0, stream>>>(x, w1, b1, xh, w1h, woh, wo,
                                          rope, wvt, bv2);
    // Wv2 = Wv @ Wv
    wv2_k<<<dim3(16, 16), blk, 0, stream>>>(w1h + (size_t)2048 * 1024, wvt, wv2);

    // GEMM1 + bias + RoPE (table) -> qkv (B,S,E2) fp16  (q,k only; v collapsed)
    gemm_f16<0><<<dim3(E2 / 128, BS / 128), blk, 0, stream>>>(
        xh, nullptr, w1h, nullptr, b1, nullptr, rope, qkv, nullptr, nullptr,
        E2, Ev, Ev);
    // GEMM2: q2/k2 from qkv (+SC on q) -> qkv2 [part][b][h][s][d];
    //        v2 = xh @ Wv2^T + bv2 -> v2t [b][h][d][s]
    gemm_f16<1><<<dim3(E3 / 128, BS / 128), blk, 0, stream>>>(
        qkv, xh, w1h, wv2, b1, bv2, nullptr, qkv2, v2t, nullptr, E3, Ev, E2);
    // flash attention -> ctx fp16
    attn_f16<<<dim3(Sv / 128, Hv, Bv), blk, 0, stream>>>(qkv2, v2t, ctx);
    // GEMM3: out = ctx @ wo^T + bo (fp32)
    gemm_f16<2><<<dim3(Ev / 128, BS / 128), blk, 0, stream>>>(
        ctx, nullptr, woh, nullptr, bo, nullptr, nullptr, nullptr, nullptr, out,
        Ev, Ev, Ev);
}